// Round 14
// baseline (515.227 us; speedup 1.0000x reference)
//
#include <hip/hip_runtime.h>
#include <cmath>

#define BLK 256
#define BSHIFT 9          // 512 nodes per bucket; ~8K edges (~65KB pairs) per bucket
#define EPT 16            // edges per thread in binning kernels
#define TILE (BLK * EPT)  // 4096 edges per tile

// ---------------- CSR build: LDS-binned bucket scatter ----------------

__global__ void bhist_kernel(const int* __restrict__ dst, int* __restrict__ bcnt,
                             int E, int nbuk) {
  __shared__ int hist[256];
  int t = threadIdx.x;
  hist[t] = 0;
  __syncthreads();
  int base = blockIdx.x * TILE;
#pragma unroll
  for (int k = 0; k < EPT; k++) {
    int e = base + k * BLK + t;
    if (e < E) atomicAdd(&hist[dst[e] >> BSHIFT], 1);
  }
  __syncthreads();
  if (t < nbuk && hist[t] > 0) atomicAdd(&bcnt[t], hist[t]);
}

__global__ void bscan_kernel(const int* __restrict__ bcnt, int* __restrict__ gbase,
                             int* __restrict__ gbcur, int nbuk, int E) {
  __shared__ int sdata[BLK];
  int t = threadIdx.x;
  int v = (t < nbuk) ? bcnt[t] : 0;
  sdata[t] = v;
  __syncthreads();
  for (int off = 1; off < BLK; off <<= 1) {
    int x = (t >= off) ? sdata[t - off] : 0;
    __syncthreads();
    sdata[t] += x;
    __syncthreads();
  }
  int excl = sdata[t] - v;
  if (t < nbuk) { gbase[t] = excl; gbcur[t] = excl; }
  if (t == 0) gbase[nbuk] = E;
}

__global__ void scatter_pairs_lds_kernel(const int* __restrict__ src, const int* __restrict__ dst,
                                         int* __restrict__ gbcur, int2* __restrict__ pairs,
                                         int E, int nbuk) {
  __shared__ int hist[256];
  __shared__ int chunk[256];
  int t = threadIdx.x;
  hist[t] = 0;
  __syncthreads();
  int base = blockIdx.x * TILE;
  int es[EPT], ed[EPT];
#pragma unroll
  for (int k = 0; k < EPT; k++) {
    int e = base + k * BLK + t;
    if (e < E) {
      es[k] = src[e];
      ed[k] = dst[e];
      atomicAdd(&hist[ed[k] >> BSHIFT], 1);
    } else {
      ed[k] = -1;
    }
  }
  __syncthreads();
  if (t < nbuk && hist[t] > 0) chunk[t] = atomicAdd(&gbcur[t], hist[t]);
  __syncthreads();
#pragma unroll
  for (int k = 0; k < EPT; k++) {
    if (ed[k] >= 0) {
      int p = atomicAdd(&chunk[ed[k] >> BSHIFT], 1);
      pairs[p] = make_int2(es[k], ed[k]);
    }
  }
}

__global__ void bucket_build_kernel(const int2* __restrict__ pairs, const int* __restrict__ gbase,
                                    int* __restrict__ row_start, int* __restrict__ csr,
                                    int n, int nbuk, int E) {
  __shared__ int cnt[512];
  __shared__ int excl[512];
  __shared__ int s2[BLK];
  int b = blockIdx.x;
  int t = threadIdx.x;
  int n0 = b << BSHIFT;
  int n1 = min(n0 + (1 << BSHIFT), n);
  int bb0 = gbase[b], bb1 = gbase[b + 1];
  cnt[t] = 0; cnt[t + 256] = 0;
  __syncthreads();
  for (int r = bb0 + t; r < bb1; r += BLK) atomicAdd(&cnt[pairs[r].y - n0], 1);
  __syncthreads();
  s2[t] = cnt[2 * t] + cnt[2 * t + 1];
  __syncthreads();
  int v = s2[t];
  for (int off = 1; off < BLK; off <<= 1) {
    int x = (t >= off) ? s2[t - off] : 0;
    __syncthreads();
    s2[t] += x;
    __syncthreads();
  }
  int e2 = s2[t] - v;
  excl[2 * t] = e2;
  excl[2 * t + 1] = e2 + cnt[2 * t];
  __syncthreads();
  for (int k = t; k < n1 - n0; k += BLK) row_start[n0 + k] = bb0 + excl[k];
  if (b == nbuk - 1 && t == 0) row_start[n] = E;
  cnt[2 * t] = bb0 + excl[2 * t];
  cnt[2 * t + 1] = bb0 + excl[2 * t + 1];
  __syncthreads();
  for (int r = bb0 + t; r < bb1; r += BLK) {
    int2 pr = pairs[r];
    int pos = atomicAdd(&cnt[pr.y - n0], 1);
    csr[pos] = pr.x;
  }
}

// ---------------- FeaSt heads=4 ----------------
// 16 threads per node = 4 edge-strides (e4) x 4 feature-quarters (f4).
// Round-13 showed per-wave ILP saturates at ~2 in-flight edge-groups (the
// quad-shfl xu-recompute locks the 4 f4-lanes in step), so deeper per-lane
// batching was null. This round doubles TLP instead: 4 edge-strides halve
// per-lane serial edges (8.5 -> 4.3) and double waves/node (occupancy 30% had
// headroom at VGPR 52). acc stays 16 floats — no spill (round-6 failure mode).
// EPI: 0 = relu->out ; 1 = raw->out ; 2 = raw->out2 AND relu->out
template <int EPI>
__global__ void gather4_kernel(const float* __restrict__ x,
                               const int* __restrict__ row_start, const int* __restrict__ csr,
                               const float* __restrict__ W, const float* __restrict__ u,
                               const float* __restrict__ c, const float* __restrict__ b,
                               float* __restrict__ out, float* __restrict__ out2, int n) {
  // transposed weight LDS: float idx = ((h*4+og)*16 + k)*4 + cc  = W[k][h*16+og*4+cc]
  __shared__ float4 sW[256];
  __shared__ float su[64];   // u 16x4 row-major
  __shared__ float sc[4];
  __shared__ float sb[16];
  {
    int t = threadIdx.x;
    for (int q = t; q < 1024; q += blockDim.x) {
      int cc = q & 3, k = (q >> 2) & 15, og = (q >> 6) & 3, h = q >> 8;
      ((float*)sW)[q] = W[k * 64 + h * 16 + og * 4 + cc];
    }
    if (t < 64) su[t] = u[t];
    if (t < 4) sc[t] = c[t];
    if (t < 16) sb[t] = b[t];
  }
  __syncthreads();
  int tid = blockIdx.x * blockDim.x + threadIdx.x;
  int i = tid >> 4;
  int e4 = (tid >> 2) & 3;
  int f4 = tid & 3;
  if (i >= n) return;

  // this lane's slice of u: rows f4*4..f4*4+3, all 4 heads (16 VGPR)
  float ul[4][4];  // [kl][h]
#pragma unroll
  for (int kl = 0; kl < 4; kl++)
#pragma unroll
    for (int h = 0; h < 4; h++) ul[kl][h] = su[(f4 * 4 + kl) * 4 + h];

  float sc0 = sc[0], sc1 = sc[1], sc2 = sc[2], sc3 = sc[3];

  // xui via quad recompute from x[i] quarter (also reused for self-loop)
  float4 xi = *(const float4*)(x + i * 16 + f4 * 4);
  float xui0, xui1, xui2, xui3;
  {
    float p0 = xi.x * ul[0][0] + xi.y * ul[1][0] + xi.z * ul[2][0] + xi.w * ul[3][0];
    float p1 = xi.x * ul[0][1] + xi.y * ul[1][1] + xi.z * ul[2][1] + xi.w * ul[3][1];
    float p2 = xi.x * ul[0][2] + xi.y * ul[1][2] + xi.z * ul[2][2] + xi.w * ul[3][2];
    float p3 = xi.x * ul[0][3] + xi.y * ul[1][3] + xi.z * ul[2][3] + xi.w * ul[3][3];
    p0 += __shfl_xor(p0, 1); p0 += __shfl_xor(p0, 2);
    p1 += __shfl_xor(p1, 1); p1 += __shfl_xor(p1, 2);
    p2 += __shfl_xor(p2, 1); p2 += __shfl_xor(p2, 2);
    p3 += __shfl_xor(p3, 1); p3 += __shfl_xor(p3, 2);
    xui0 = p0; xui1 = p1; xui2 = p2; xui3 = p3;
  }

  float acc[4][4];  // [head][local feature], global k = f4*4 + kl
#pragma unroll
  for (int h = 0; h < 4; h++)
#pragma unroll
    for (int kl = 0; kl < 4; kl++) acc[h][kl] = 0.f;

  // one edge: recompute xu[j] across the quad, softmax, accumulate
  auto process = [&](const float4& v) {
    float t0 = v.x * ul[0][0] + v.y * ul[1][0] + v.z * ul[2][0] + v.w * ul[3][0];
    float t1 = v.x * ul[0][1] + v.y * ul[1][1] + v.z * ul[2][1] + v.w * ul[3][1];
    float t2 = v.x * ul[0][2] + v.y * ul[1][2] + v.z * ul[2][2] + v.w * ul[3][2];
    float t3 = v.x * ul[0][3] + v.y * ul[1][3] + v.z * ul[2][3] + v.w * ul[3][3];
    t0 += __shfl_xor(t0, 1); t0 += __shfl_xor(t0, 2);
    t1 += __shfl_xor(t1, 1); t1 += __shfl_xor(t1, 2);
    t2 += __shfl_xor(t2, 1); t2 += __shfl_xor(t2, 2);
    t3 += __shfl_xor(t3, 1); t3 += __shfl_xor(t3, 2);
    float l0 = t0 - xui0 + sc0;
    float l1 = t1 - xui1 + sc1;
    float l2 = t2 - xui2 + sc2;
    float l3 = t3 - xui3 + sc3;
    float m = fmaxf(fmaxf(l0, l1), fmaxf(l2, l3));
    float q0 = __expf(l0 - m), q1 = __expf(l1 - m), q2 = __expf(l2 - m), q3 = __expf(l3 - m);
    float inv = 1.0f / (q0 + q1 + q2 + q3);
    q0 *= inv; q1 *= inv; q2 *= inv; q3 *= inv;
    acc[0][0] += q0 * v.x; acc[0][1] += q0 * v.y; acc[0][2] += q0 * v.z; acc[0][3] += q0 * v.w;
    acc[1][0] += q1 * v.x; acc[1][1] += q1 * v.y; acc[1][2] += q1 * v.z; acc[1][3] += q1 * v.w;
    acc[2][0] += q2 * v.x; acc[2][1] += q2 * v.y; acc[2][2] += q2 * v.z; acc[2][3] += q2 * v.w;
    acc[3][0] += q3 * v.x; acc[3][1] += q3 * v.y; acc[3][2] += q3 * v.z; acc[3][3] += q3 * v.w;
  };

  // self loop (q = softmax(c)) on the e4==3 lanes
  if (e4 == 3) {
    float m = fmaxf(fmaxf(sc0, sc1), fmaxf(sc2, sc3));
    float q0 = __expf(sc0 - m), q1 = __expf(sc1 - m), q2 = __expf(sc2 - m), q3 = __expf(sc3 - m);
    float inv = 1.0f / (q0 + q1 + q2 + q3);
    q0 *= inv; q1 *= inv; q2 *= inv; q3 *= inv;
    acc[0][0] += q0 * xi.x; acc[0][1] += q0 * xi.y; acc[0][2] += q0 * xi.z; acc[0][3] += q0 * xi.w;
    acc[1][0] += q1 * xi.x; acc[1][1] += q1 * xi.y; acc[1][2] += q1 * xi.z; acc[1][3] += q1 * xi.w;
    acc[2][0] += q2 * xi.x; acc[2][1] += q2 * xi.y; acc[2][2] += q2 * xi.z; acc[2][3] += q2 * xi.w;
    acc[3][0] += q3 * xi.x; acc[3][1] += q3 * xi.y; acc[3][2] += q3 * xi.z; acc[3][3] += q3 * xi.w;
  }

  int r0 = row_start[i], r1 = row_start[i + 1];
  int r = r0 + e4;
  // pair-batched loads (stride 4 per e-stride lane)
  for (; r + 4 < r1; r += 8) {
    int ja = csr[r];
    int jb = csr[r + 4];
    float4 va = *(const float4*)(x + ja * 16 + f4 * 4);
    float4 vb = *(const float4*)(x + jb * 16 + f4 * 4);
    process(va);
    process(vb);
  }
  if (r < r1) {
    int j = csr[r];
    float4 v = *(const float4*)(x + j * 16 + f4 * 4);
    process(v);
  }

  // reduce over the 4 e4 strides (lane bits 2-3)
#pragma unroll
  for (int h = 0; h < 4; h++)
#pragma unroll
    for (int kl = 0; kl < 4; kl++) {
      float v = acc[h][kl];
      v += __shfl_xor(v, 4);
      v += __shfl_xor(v, 8);
      acc[h][kl] = v;
    }

  // per-lane partials for ALL 16 outputs from this lane's k-quarter (256 FMA)
  float p[4][4];  // [og][cc]
#pragma unroll
  for (int og = 0; og < 4; og++)
#pragma unroll
    for (int cc = 0; cc < 4; cc++) p[og][cc] = 0.f;
#pragma unroll
  for (int kl = 0; kl < 4; kl++) {
#pragma unroll
    for (int h = 0; h < 4; h++) {
      float a = acc[h][kl];
#pragma unroll
      for (int og = 0; og < 4; og++) {
        float4 w = sW[(h * 4 + og) * 16 + f4 * 4 + kl];
        p[og][0] += a * w.x; p[og][1] += a * w.y; p[og][2] += a * w.z; p[og][3] += a * w.w;
      }
    }
  }
  // reduce over the 4 f4 lanes
#pragma unroll
  for (int og = 0; og < 4; og++)
#pragma unroll
    for (int cc = 0; cc < 4; cc++) {
      float v = p[og][cc];
      v += __shfl_xor(v, 1);
      v += __shfl_xor(v, 2);
      p[og][cc] = v;
    }

  if (e4 == 0) {  // lane f4 writes output quarter og = f4 (compile-time selects)
    float invdeg = 1.0f / (float)(r1 - r0 + 1);
    float o0, o1, o2, o3;
    if (f4 == 0)      { o0 = p[0][0]; o1 = p[0][1]; o2 = p[0][2]; o3 = p[0][3]; }
    else if (f4 == 1) { o0 = p[1][0]; o1 = p[1][1]; o2 = p[1][2]; o3 = p[1][3]; }
    else if (f4 == 2) { o0 = p[2][0]; o1 = p[2][1]; o2 = p[2][2]; o3 = p[2][3]; }
    else              { o0 = p[3][0]; o1 = p[3][1]; o2 = p[3][2]; o3 = p[3][3]; }
    o0 = o0 * invdeg + sb[f4 * 4 + 0];
    o1 = o1 * invdeg + sb[f4 * 4 + 1];
    o2 = o2 * invdeg + sb[f4 * 4 + 2];
    o3 = o3 * invdeg + sb[f4 * 4 + 3];
    if (EPI == 1) {
      *(float4*)(out + i * 16 + f4 * 4) = make_float4(o0, o1, o2, o3);
    } else if (EPI == 0) {
      *(float4*)(out + i * 16 + f4 * 4) =
          make_float4(fmaxf(o0, 0.f), fmaxf(o1, 0.f), fmaxf(o2, 0.f), fmaxf(o3, 0.f));
    } else {
      *(float4*)(out2 + i * 16 + f4 * 4) = make_float4(o0, o1, o2, o3);
      *(float4*)(out + i * 16 + f4 * 4) =
          make_float4(fmaxf(o0, 0.f), fmaxf(o1, 0.f), fmaxf(o2, 0.f), fmaxf(o3, 0.f));
    }
  }
}

// ---------------- FeaSt heads=1 (softmax over 1 head == 1: pure mean agg + matvec) ----------------
// Cooperative 8-lane decomposition; batch-8 independent loads per lane.

template <int RELU>
__global__ void gather1_kernel(const float* __restrict__ x, const int* __restrict__ row_start,
                               const int* __restrict__ csr, const float* __restrict__ W,
                               const float* __restrict__ b, float* __restrict__ out, int n) {
  // transposed weight LDS: float idx = (og*16 + k)*4 + cc = W[k][og*4+cc]
  __shared__ float4 sW[64];
  __shared__ float sb[16];
  {
    int t = threadIdx.x;
    if (t < 256) {
      int cc = t & 3, k = (t >> 2) & 15, og = t >> 6;
      ((float*)sW)[t] = W[k * 16 + og * 4 + cc];
    }
    if (t < 16) sb[t] = b[t];
  }
  __syncthreads();
  int tid = blockIdx.x * blockDim.x + threadIdx.x;
  int i = tid >> 3;
  int e2 = (tid >> 2) & 1;
  int f4 = tid & 3;
  if (i >= n) return;

  float acc[4] = {0.f, 0.f, 0.f, 0.f};  // features f4*4 .. f4*4+4

  if (e2 == 1) {  // self loop
    float4 v = *(const float4*)(x + i * 16 + f4 * 4);
    acc[0] += v.x; acc[1] += v.y; acc[2] += v.z; acc[3] += v.w;
  }

  int r0 = row_start[i], r1 = row_start[i + 1];
  int r = r0 + e2;
  for (; r + 14 < r1; r += 16) {
    int j0 = csr[r],      j1 = csr[r + 2],  j2 = csr[r + 4],  j3 = csr[r + 6];
    int j4 = csr[r + 8],  j5 = csr[r + 10], j6 = csr[r + 12], j7 = csr[r + 14];
    float4 v0 = *(const float4*)(x + j0 * 16 + f4 * 4);
    float4 v1 = *(const float4*)(x + j1 * 16 + f4 * 4);
    float4 v2 = *(const float4*)(x + j2 * 16 + f4 * 4);
    float4 v3 = *(const float4*)(x + j3 * 16 + f4 * 4);
    float4 v4 = *(const float4*)(x + j4 * 16 + f4 * 4);
    float4 v5 = *(const float4*)(x + j5 * 16 + f4 * 4);
    float4 v6 = *(const float4*)(x + j6 * 16 + f4 * 4);
    float4 v7 = *(const float4*)(x + j7 * 16 + f4 * 4);
    acc[0] += (v0.x + v1.x) + (v2.x + v3.x) + (v4.x + v5.x) + (v6.x + v7.x);
    acc[1] += (v0.y + v1.y) + (v2.y + v3.y) + (v4.y + v5.y) + (v6.y + v7.y);
    acc[2] += (v0.z + v1.z) + (v2.z + v3.z) + (v4.z + v5.z) + (v6.z + v7.z);
    acc[3] += (v0.w + v1.w) + (v2.w + v3.w) + (v4.w + v5.w) + (v6.w + v7.w);
  }
  for (; r + 6 < r1; r += 8) {
    int j0 = csr[r], j1 = csr[r + 2], j2 = csr[r + 4], j3 = csr[r + 6];
    float4 v0 = *(const float4*)(x + j0 * 16 + f4 * 4);
    float4 v1 = *(const float4*)(x + j1 * 16 + f4 * 4);
    float4 v2 = *(const float4*)(x + j2 * 16 + f4 * 4);
    float4 v3 = *(const float4*)(x + j3 * 16 + f4 * 4);
    acc[0] += v0.x + v1.x + v2.x + v3.x;
    acc[1] += v0.y + v1.y + v2.y + v3.y;
    acc[2] += v0.z + v1.z + v2.z + v3.z;
    acc[3] += v0.w + v1.w + v2.w + v3.w;
  }
  for (; r < r1; r += 2) {
    int j = csr[r];
    float4 v = *(const float4*)(x + j * 16 + f4 * 4);
    acc[0] += v.x; acc[1] += v.y; acc[2] += v.z; acc[3] += v.w;
  }

#pragma unroll
  for (int kl = 0; kl < 4; kl++) acc[kl] += __shfl_xor(acc[kl], 4);

  // per-lane partials for all 16 outputs from this k-quarter (64 FMA)
  float p[4][4];
#pragma unroll
  for (int og = 0; og < 4; og++)
#pragma unroll
    for (int cc = 0; cc < 4; cc++) p[og][cc] = 0.f;
#pragma unroll
  for (int kl = 0; kl < 4; kl++) {
    float a = acc[kl];
#pragma unroll
    for (int og = 0; og < 4; og++) {
      float4 w = sW[og * 16 + f4 * 4 + kl];
      p[og][0] += a * w.x; p[og][1] += a * w.y; p[og][2] += a * w.z; p[og][3] += a * w.w;
    }
  }
#pragma unroll
  for (int og = 0; og < 4; og++)
#pragma unroll
    for (int cc = 0; cc < 4; cc++) {
      float v = p[og][cc];
      v += __shfl_xor(v, 1);
      v += __shfl_xor(v, 2);
      p[og][cc] = v;
    }

  if (e2 == 0) {
    float invdeg = 1.0f / (float)(r1 - r0 + 1);
    float o0, o1, o2, o3;
    if (f4 == 0)      { o0 = p[0][0]; o1 = p[0][1]; o2 = p[0][2]; o3 = p[0][3]; }
    else if (f4 == 1) { o0 = p[1][0]; o1 = p[1][1]; o2 = p[1][2]; o3 = p[1][3]; }
    else if (f4 == 2) { o0 = p[2][0]; o1 = p[2][1]; o2 = p[2][2]; o3 = p[2][3]; }
    else              { o0 = p[3][0]; o1 = p[3][1]; o2 = p[3][2]; o3 = p[3][3]; }
    o0 = o0 * invdeg + sb[f4 * 4 + 0];
    o1 = o1 * invdeg + sb[f4 * 4 + 1];
    o2 = o2 * invdeg + sb[f4 * 4 + 2];
    o3 = o3 * invdeg + sb[f4 * 4 + 3];
    if (RELU) {
      o0 = fmaxf(o0, 0.f); o1 = fmaxf(o1, 0.f); o2 = fmaxf(o2, 0.f); o3 = fmaxf(o3, 0.f);
    }
    *(float4*)(out + i * 16 + f4 * 4) = make_float4(o0, o1, o2, o3);
  }
}

// ---------------- BatchNorm ----------------

__global__ void bn_stats_kernel(const float* __restrict__ x, float* __restrict__ stats, int n) {
  __shared__ float wbuf[4][32];
  int t = threadIdx.x;
  float ls[16], lq[16];
#pragma unroll
  for (int k = 0; k < 16; k++) { ls[k] = 0.f; lq[k] = 0.f; }
  for (int i = blockIdx.x * blockDim.x + t; i < n; i += gridDim.x * blockDim.x) {
    const float4* xi = (const float4*)(x + i * 16);
#pragma unroll
    for (int g = 0; g < 4; g++) {
      float4 v = xi[g];
      ls[g * 4 + 0] += v.x; lq[g * 4 + 0] += v.x * v.x;
      ls[g * 4 + 1] += v.y; lq[g * 4 + 1] += v.y * v.y;
      ls[g * 4 + 2] += v.z; lq[g * 4 + 2] += v.z * v.z;
      ls[g * 4 + 3] += v.w; lq[g * 4 + 3] += v.w * v.w;
    }
  }
#pragma unroll
  for (int k = 0; k < 16; k++) {
    for (int off = 1; off < 64; off <<= 1) {
      ls[k] += __shfl_xor(ls[k], off);
      lq[k] += __shfl_xor(lq[k], off);
    }
  }
  int wid = t >> 6, lane = t & 63;
  if (lane < 16) wbuf[wid][lane] = ls[lane];
  if (lane >= 16 && lane < 32) wbuf[wid][lane] = lq[lane - 16];
  __syncthreads();
  if (t < 32) {
    float s = wbuf[0][t] + wbuf[1][t] + wbuf[2][t] + wbuf[3][t];
    atomicAdd(&stats[t], s);
  }
}

// RESID: out = relu(bn(x)) (+ r1 + r2 if RESID)
template <int RESID>
__global__ void bn_apply_kernel(const float* __restrict__ x, const float* __restrict__ stats,
                                const float* __restrict__ g, const float* __restrict__ be,
                                const float* __restrict__ r1, const float* __restrict__ r2,
                                float* __restrict__ out, int n) {
  __shared__ float sscale[16], sshift[16];
  int t = threadIdx.x;
  if (t < 16) {
    float invn = 1.0f / (float)n;
    float mu = stats[t] * invn;
    float var = stats[16 + t] * invn - mu * mu;
    float sc = g[t] * rsqrtf(var + 1e-5f);
    sscale[t] = sc;
    sshift[t] = be[t] - mu * sc;
  }
  __syncthreads();
  int i = blockIdx.x * blockDim.x + t;
  if (i >= n) return;
#pragma unroll
  for (int og = 0; og < 4; og++) {
    float4 v = *(const float4*)(x + i * 16 + og * 4);
    float o0 = fmaxf(v.x * sscale[og * 4 + 0] + sshift[og * 4 + 0], 0.f);
    float o1 = fmaxf(v.y * sscale[og * 4 + 1] + sshift[og * 4 + 1], 0.f);
    float o2 = fmaxf(v.z * sscale[og * 4 + 2] + sshift[og * 4 + 2], 0.f);
    float o3 = fmaxf(v.w * sscale[og * 4 + 3] + sshift[og * 4 + 3], 0.f);
    if (RESID) {
      float4 a = *(const float4*)(r1 + i * 16 + og * 4);
      float4 bb = *(const float4*)(r2 + i * 16 + og * 4);
      o0 += a.x + bb.x; o1 += a.y + bb.y; o2 += a.z + bb.z; o3 += a.w + bb.w;
    }
    *(float4*)(out + i * 16 + og * 4) = make_float4(o0, o1, o2, o3);
  }
}

// ---------------- MLP head: 16 ->64 relu ->64 relu ->16 relu ->1 sigmoid ----------------
// 4 threads per node; lane sub owns activations [sub*16, sub*16+16) (no spill).

__global__ void mlp_kernel(const float* __restrict__ h,
                           const float* __restrict__ lw1, const float* __restrict__ lb1,
                           const float* __restrict__ lw2, const float* __restrict__ lb2,
                           const float* __restrict__ lw3, const float* __restrict__ lb3,
                           const float* __restrict__ ow, const float* __restrict__ ob,
                           float* __restrict__ out, int n) {
  __shared__ float4 s1[256];   // 16x64, float4 idx = k*16 + og
  __shared__ float4 s2[1024];  // 64x64
  __shared__ float4 s3[256];   // 64x16
  __shared__ float sb1[64], sb2[64], sb3[16], sow[16], sob[1];
  {
    int t = threadIdx.x;
    for (int k = t; k < 1024; k += blockDim.x) ((float*)s1)[k] = lw1[k];
    for (int k = t; k < 4096; k += blockDim.x) ((float*)s2)[k] = lw2[k];
    for (int k = t; k < 1024; k += blockDim.x) ((float*)s3)[k] = lw3[k];
    if (t < 64) sb1[t] = lb1[t];
    if (t < 64) sb2[t] = lb2[t];
    if (t < 16) sb3[t] = lb3[t];
    if (t < 16) sow[t] = ow[t];
    if (t == 0) sob[0] = ob[0];
  }
  __syncthreads();
  int tid = blockIdx.x * blockDim.x + threadIdx.x;
  int i = tid >> 2;
  int sub = tid & 3;
  if (i >= n) return;

  float4 inq = *(const float4*)(h + i * 16 + sub * 4);
  float in4[4] = {inq.x, inq.y, inq.z, inq.w};

  float a[16];
#pragma unroll
  for (int g = 0; g < 4; g++) {
    int og = sub * 4 + g;
    a[g * 4 + 0] = sb1[og * 4 + 0]; a[g * 4 + 1] = sb1[og * 4 + 1];
    a[g * 4 + 2] = sb1[og * 4 + 2]; a[g * 4 + 3] = sb1[og * 4 + 3];
  }
#pragma unroll
  for (int k = 0; k < 16; k++) {
    float v = __shfl(in4[k & 3], k >> 2, 4);
#pragma unroll
    for (int g = 0; g < 4; g++) {
      float4 w = s1[k * 16 + sub * 4 + g];
      a[g * 4 + 0] += v * w.x; a[g * 4 + 1] += v * w.y;
      a[g * 4 + 2] += v * w.z; a[g * 4 + 3] += v * w.w;
    }
  }
#pragma unroll
  for (int k = 0; k < 16; k++) a[k] = fmaxf(a[k], 0.f);

  float b2[16];
#pragma unroll
  for (int g = 0; g < 4; g++) {
    int og = sub * 4 + g;
    b2[g * 4 + 0] = sb2[og * 4 + 0]; b2[g * 4 + 1] = sb2[og * 4 + 1];
    b2[g * 4 + 2] = sb2[og * 4 + 2]; b2[g * 4 + 3] = sb2[og * 4 + 3];
  }
#pragma unroll
  for (int k = 0; k < 64; k++) {
    float v = __shfl(a[k & 15], k >> 4, 4);
#pragma unroll
    for (int g = 0; g < 4; g++) {
      float4 w = s2[k * 16 + sub * 4 + g];
      b2[g * 4 + 0] += v * w.x; b2[g * 4 + 1] += v * w.y;
      b2[g * 4 + 2] += v * w.z; b2[g * 4 + 3] += v * w.w;
    }
  }
#pragma unroll
  for (int k = 0; k < 16; k++) b2[k] = fmaxf(b2[k], 0.f);

  float c0 = sb3[sub * 4 + 0], c1 = sb3[sub * 4 + 1], c2 = sb3[sub * 4 + 2], c3v = sb3[sub * 4 + 3];
#pragma unroll
  for (int k = 0; k < 64; k++) {
    float v = __shfl(b2[k & 15], k >> 4, 4);
    float4 w = s3[k * 4 + sub];
    c0 += v * w.x; c1 += v * w.y; c2 += v * w.z; c3v += v * w.w;
  }
  c0 = fmaxf(c0, 0.f); c1 = fmaxf(c1, 0.f); c2 = fmaxf(c2, 0.f); c3v = fmaxf(c3v, 0.f);

  float zp = c0 * sow[sub * 4 + 0] + c1 * sow[sub * 4 + 1] +
             c2 * sow[sub * 4 + 2] + c3v * sow[sub * 4 + 3];
  zp += __shfl_xor(zp, 1);
  zp += __shfl_xor(zp, 2);
  if (sub == 0) out[i] = 1.0f / (1.0f + __expf(-(zp + sob[0])));
}

// ---------------- launch ----------------

extern "C" void kernel_launch(void* const* d_in, const int* in_sizes, int n_in,
                              void* d_out, int out_size, void* d_ws, size_t ws_size,
                              hipStream_t stream) {
  const float* x = (const float*)d_in[0];
  const int* ei = (const int*)d_in[1];
  const int N = in_sizes[0] / 16;
  const int E = in_sizes[1] / 2;
  const int* srcp = ei;
  const int* dstp = ei + E;

  const float* W1 = (const float*)d_in[2];  const float* u1 = (const float*)d_in[3];
  const float* c1 = (const float*)d_in[4];  const float* b1 = (const float*)d_in[5];
  const float* W2 = (const float*)d_in[6];  const float* u2 = (const float*)d_in[7];
  const float* c2 = (const float*)d_in[8];  const float* b2 = (const float*)d_in[9];
  const float* W3 = (const float*)d_in[10]; const float* u3 = (const float*)d_in[11];
  const float* c3 = (const float*)d_in[12]; const float* b3 = (const float*)d_in[13];
  const float* W4 = (const float*)d_in[14]; const float* b4 = (const float*)d_in[17];
  const float* W5 = (const float*)d_in[18]; const float* b5 = (const float*)d_in[21];
  const float* W6 = (const float*)d_in[22]; const float* b6 = (const float*)d_in[25];
  const float* g1 = (const float*)d_in[26]; const float* be1 = (const float*)d_in[27];
  const float* g2 = (const float*)d_in[28]; const float* be2 = (const float*)d_in[29];
  const float* lw1 = (const float*)d_in[30]; const float* lb1 = (const float*)d_in[31];
  const float* lw2 = (const float*)d_in[32]; const float* lb2 = (const float*)d_in[33];
  const float* lw3 = (const float*)d_in[34]; const float* lb3 = (const float*)d_in[35];
  const float* ow = (const float*)d_in[36]; const float* ob = (const float*)d_in[37];
  float* out = (float*)d_out;

  char* ws = (char*)d_ws;
  size_t off = 0;
  auto alloc = [&](size_t bytes) -> void* {
    void* p = ws + off;
    off = (off + bytes + 255) & ~(size_t)255;
    return p;
  };
  int* row_start = (int*)alloc((size_t)(N + 1) * 4);
  int* csr = (int*)alloc((size_t)E * 4);
  float* bufA = (float*)alloc((size_t)N * 16 * 4);
  float* bufB = (float*)alloc((size_t)N * 16 * 4);
  float* h2b = (float*)alloc((size_t)N * 16 * 4);
  float* h4b = (float*)alloc((size_t)N * 16 * 4);
  float* tmp = (float*)alloc((size_t)N * 16 * 4);
  float* stats = (float*)alloc(32 * 4);
  const int NBUK = (N + (1 << BSHIFT) - 1) >> BSHIFT;
  int* bcnt = (int*)alloc((size_t)NBUK * 4);
  int* gbase = (int*)alloc((size_t)(NBUK + 1) * 4);
  int* gbcur = (int*)alloc((size_t)NBUK * 4);
  // pairs staging (E * 8B = 12.8MB) aliases bufA+bufB (contiguous 12.8MB),
  // unused until layer 1 (CSR build completes first).
  int2* pairs = (int2*)bufA;

  const int NB = (N + BLK - 1) / BLK;         // node-parallel grid
  const int NG4 = (4 * N + BLK - 1) / BLK;    // 4-threads-per-node (mlp)
  const int NG8 = (8 * N + BLK - 1) / BLK;    // 8-threads-per-node (gather1)
  const int NG16 = (16 * N + BLK - 1) / BLK;  // 16-threads-per-node (gather4)
  const int NT = (E + TILE - 1) / TILE;       // edge tiles

  // ---- CSR build (per call; ws is re-poisoned every launch) ----
  hipMemsetAsync(bcnt, 0, (size_t)NBUK * 4, stream);
  bhist_kernel<<<NT, BLK, 0, stream>>>(dstp, bcnt, E, NBUK);
  bscan_kernel<<<1, BLK, 0, stream>>>(bcnt, gbase, gbcur, NBUK, E);
  scatter_pairs_lds_kernel<<<NT, BLK, 0, stream>>>(srcp, dstp, gbcur, pairs, E, NBUK);
  bucket_build_kernel<<<NBUK, BLK, 0, stream>>>(pairs, gbase, row_start, csr, N, NBUK, E);

  // ---- Layer 1: h = relu(feast4(x)) -> bufA ----
  gather4_kernel<0><<<NG16, BLK, 0, stream>>>(x, row_start, csr, W1, u1, c1, b1, bufA, nullptr, N);

  // ---- Layer 2: h2 = feast4(bufA) (raw -> h2b), relu -> bufB ----
  gather4_kernel<2><<<NG16, BLK, 0, stream>>>(bufA, row_start, csr, W2, u2, c2, b2, bufB, h2b, N);

  // ---- Layer 3: h3 = relu(bn(feast4(bufB))) -> bufA ----
  gather4_kernel<1><<<NG16, BLK, 0, stream>>>(bufB, row_start, csr, W3, u3, c3, b3, tmp, nullptr, N);
  hipMemsetAsync(stats, 0, 32 * 4, stream);
  bn_stats_kernel<<<256, BLK, 0, stream>>>(tmp, stats, N);
  bn_apply_kernel<0><<<NB, BLK, 0, stream>>>(tmp, stats, g1, be1, nullptr, nullptr, bufA, N);

  // ---- Layer 4: h4 = relu(feast1(bufA)) -> h4b ----
  gather1_kernel<1><<<NG8, BLK, 0, stream>>>(bufA, row_start, csr, W4, b4, h4b, N);

  // ---- Layer 5: h5 = relu(feast1(h4b)) -> bufB ----
  gather1_kernel<1><<<NG8, BLK, 0, stream>>>(h4b, row_start, csr, W5, b5, bufB, N);

  // ---- Layer 6: h6 = relu(bn(feast1(bufB))) + h2b + h4b -> bufA ----
  gather1_kernel<0><<<NG8, BLK, 0, stream>>>(bufB, row_start, csr, W6, b6, tmp, N);
  hipMemsetAsync(stats, 0, 32 * 4, stream);
  bn_stats_kernel<<<256, BLK, 0, stream>>>(tmp, stats, N);
  bn_apply_kernel<1><<<NB, BLK, 0, stream>>>(tmp, stats, g2, be2, h2b, h4b, bufA, N);

  // ---- MLP head -> out ----
  mlp_kernel<<<NG4, BLK, 0, stream>>>(bufA, lw1, lb1, lw2, lb2, lw3, lb3, ow, ob, out, N);
}

// Round 15
// 462.288 us; speedup vs baseline: 1.1145x; 1.1145x over previous
//
#include <hip/hip_runtime.h>
#include <cmath>

#define BLK 256
#define BSHIFT 9          // 512 nodes per bucket; ~8K edges (~65KB pairs) per bucket
#define EPT 16            // edges per thread in binning kernels
#define TILE (BLK * EPT)  // 4096 edges per tile

// ---------------- CSR build: LDS-binned bucket scatter ----------------

__global__ void bhist_kernel(const int* __restrict__ dst, int* __restrict__ bcnt,
                             int E, int nbuk) {
  __shared__ int hist[256];
  int t = threadIdx.x;
  hist[t] = 0;
  __syncthreads();
  int base = blockIdx.x * TILE;
#pragma unroll
  for (int k = 0; k < EPT; k++) {
    int e = base + k * BLK + t;
    if (e < E) atomicAdd(&hist[dst[e] >> BSHIFT], 1);
  }
  __syncthreads();
  if (t < nbuk && hist[t] > 0) atomicAdd(&bcnt[t], hist[t]);
}

__global__ void bscan_kernel(const int* __restrict__ bcnt, int* __restrict__ gbase,
                             int* __restrict__ gbcur, int nbuk, int E) {
  __shared__ int sdata[BLK];
  int t = threadIdx.x;
  int v = (t < nbuk) ? bcnt[t] : 0;
  sdata[t] = v;
  __syncthreads();
  for (int off = 1; off < BLK; off <<= 1) {
    int x = (t >= off) ? sdata[t - off] : 0;
    __syncthreads();
    sdata[t] += x;
    __syncthreads();
  }
  int excl = sdata[t] - v;
  if (t < nbuk) { gbase[t] = excl; gbcur[t] = excl; }
  if (t == 0) gbase[nbuk] = E;
}

__global__ void scatter_pairs_lds_kernel(const int* __restrict__ src, const int* __restrict__ dst,
                                         int* __restrict__ gbcur, int2* __restrict__ pairs,
                                         int E, int nbuk) {
  __shared__ int hist[256];
  __shared__ int chunk[256];
  int t = threadIdx.x;
  hist[t] = 0;
  __syncthreads();
  int base = blockIdx.x * TILE;
  int es[EPT], ed[EPT];
#pragma unroll
  for (int k = 0; k < EPT; k++) {
    int e = base + k * BLK + t;
    if (e < E) {
      es[k] = src[e];
      ed[k] = dst[e];
      atomicAdd(&hist[ed[k] >> BSHIFT], 1);
    } else {
      ed[k] = -1;
    }
  }
  __syncthreads();
  if (t < nbuk && hist[t] > 0) chunk[t] = atomicAdd(&gbcur[t], hist[t]);
  __syncthreads();
#pragma unroll
  for (int k = 0; k < EPT; k++) {
    if (ed[k] >= 0) {
      int p = atomicAdd(&chunk[ed[k] >> BSHIFT], 1);
      pairs[p] = make_int2(es[k], ed[k]);
    }
  }
}

__global__ void bucket_build_kernel(const int2* __restrict__ pairs, const int* __restrict__ gbase,
                                    int* __restrict__ row_start, int* __restrict__ csr,
                                    int n, int nbuk, int E) {
  __shared__ int cnt[512];
  __shared__ int excl[512];
  __shared__ int s2[BLK];
  int b = blockIdx.x;
  int t = threadIdx.x;
  int n0 = b << BSHIFT;
  int n1 = min(n0 + (1 << BSHIFT), n);
  int bb0 = gbase[b], bb1 = gbase[b + 1];
  cnt[t] = 0; cnt[t + 256] = 0;
  __syncthreads();
  for (int r = bb0 + t; r < bb1; r += BLK) atomicAdd(&cnt[pairs[r].y - n0], 1);
  __syncthreads();
  s2[t] = cnt[2 * t] + cnt[2 * t + 1];
  __syncthreads();
  int v = s2[t];
  for (int off = 1; off < BLK; off <<= 1) {
    int x = (t >= off) ? s2[t - off] : 0;
    __syncthreads();
    s2[t] += x;
    __syncthreads();
  }
  int e2 = s2[t] - v;
  excl[2 * t] = e2;
  excl[2 * t + 1] = e2 + cnt[2 * t];
  __syncthreads();
  for (int k = t; k < n1 - n0; k += BLK) row_start[n0 + k] = bb0 + excl[k];
  if (b == nbuk - 1 && t == 0) row_start[n] = E;
  cnt[2 * t] = bb0 + excl[2 * t];
  cnt[2 * t + 1] = bb0 + excl[2 * t + 1];
  __syncthreads();
  for (int r = bb0 + t; r < bb1; r += BLK) {
    int2 pr = pairs[r];
    int pos = atomicAdd(&cnt[pr.y - n0], 1);
    csr[pos] = pr.x;
  }
}

// ---------------- FeaSt heads=4 ----------------
// BEST VERIFIED CONFIG (round 13, 464.8us total): 8 threads/node =
// 2 edge-strides (e2) x 4 feature-quarters (f4); xu recomputed in-register
// (FETCH at the ~53MB compulsory floor = 8 XCDs x working set); batch-4 load
// groups. Measured dead ends: deeper ILP null (quad-shfl locks f4-lanes in
// step, ~2 in-flight groups max); 16 lanes/node regressed (2x epilogue work,
// occupancy didn't scale); NT csr loads regressed; L2-residency splits failed.
// EPI: 0 = relu->out ; 1 = raw->out ; 2 = raw->out2 AND relu->out
template <int EPI>
__global__ void gather4_kernel(const float* __restrict__ x,
                               const int* __restrict__ row_start, const int* __restrict__ csr,
                               const float* __restrict__ W, const float* __restrict__ u,
                               const float* __restrict__ c, const float* __restrict__ b,
                               float* __restrict__ out, float* __restrict__ out2, int n) {
  // transposed weight LDS: float idx = ((h*4+og)*16 + k)*4 + cc  = W[k][h*16+og*4+cc]
  __shared__ float4 sW[256];
  __shared__ float su[64];   // u 16x4 row-major
  __shared__ float sc[4];
  __shared__ float sb[16];
  {
    int t = threadIdx.x;
    for (int q = t; q < 1024; q += blockDim.x) {
      int cc = q & 3, k = (q >> 2) & 15, og = (q >> 6) & 3, h = q >> 8;
      ((float*)sW)[q] = W[k * 64 + h * 16 + og * 4 + cc];
    }
    if (t < 64) su[t] = u[t];
    if (t < 4) sc[t] = c[t];
    if (t < 16) sb[t] = b[t];
  }
  __syncthreads();
  int tid = blockIdx.x * blockDim.x + threadIdx.x;
  int i = tid >> 3;
  int e2 = (tid >> 2) & 1;
  int f4 = tid & 3;
  if (i >= n) return;

  // this lane's slice of u: rows f4*4..f4*4+3, all 4 heads (16 VGPR)
  float ul[4][4];  // [kl][h]
#pragma unroll
  for (int kl = 0; kl < 4; kl++)
#pragma unroll
    for (int h = 0; h < 4; h++) ul[kl][h] = su[(f4 * 4 + kl) * 4 + h];

  float sc0 = sc[0], sc1 = sc[1], sc2 = sc[2], sc3 = sc[3];

  // xui via quad recompute from x[i] quarter (also reused for self-loop)
  float4 xi = *(const float4*)(x + i * 16 + f4 * 4);
  float xui0, xui1, xui2, xui3;
  {
    float p0 = xi.x * ul[0][0] + xi.y * ul[1][0] + xi.z * ul[2][0] + xi.w * ul[3][0];
    float p1 = xi.x * ul[0][1] + xi.y * ul[1][1] + xi.z * ul[2][1] + xi.w * ul[3][1];
    float p2 = xi.x * ul[0][2] + xi.y * ul[1][2] + xi.z * ul[2][2] + xi.w * ul[3][2];
    float p3 = xi.x * ul[0][3] + xi.y * ul[1][3] + xi.z * ul[2][3] + xi.w * ul[3][3];
    p0 += __shfl_xor(p0, 1); p0 += __shfl_xor(p0, 2);
    p1 += __shfl_xor(p1, 1); p1 += __shfl_xor(p1, 2);
    p2 += __shfl_xor(p2, 1); p2 += __shfl_xor(p2, 2);
    p3 += __shfl_xor(p3, 1); p3 += __shfl_xor(p3, 2);
    xui0 = p0; xui1 = p1; xui2 = p2; xui3 = p3;
  }

  float acc[4][4];  // [head][local feature], global k = f4*4 + kl
#pragma unroll
  for (int h = 0; h < 4; h++)
#pragma unroll
    for (int kl = 0; kl < 4; kl++) acc[h][kl] = 0.f;

  // one edge: recompute xu[j] across the quad, softmax, accumulate
  auto process = [&](const float4& v) {
    float t0 = v.x * ul[0][0] + v.y * ul[1][0] + v.z * ul[2][0] + v.w * ul[3][0];
    float t1 = v.x * ul[0][1] + v.y * ul[1][1] + v.z * ul[2][1] + v.w * ul[3][1];
    float t2 = v.x * ul[0][2] + v.y * ul[1][2] + v.z * ul[2][2] + v.w * ul[3][2];
    float t3 = v.x * ul[0][3] + v.y * ul[1][3] + v.z * ul[2][3] + v.w * ul[3][3];
    t0 += __shfl_xor(t0, 1); t0 += __shfl_xor(t0, 2);
    t1 += __shfl_xor(t1, 1); t1 += __shfl_xor(t1, 2);
    t2 += __shfl_xor(t2, 1); t2 += __shfl_xor(t2, 2);
    t3 += __shfl_xor(t3, 1); t3 += __shfl_xor(t3, 2);
    float l0 = t0 - xui0 + sc0;
    float l1 = t1 - xui1 + sc1;
    float l2 = t2 - xui2 + sc2;
    float l3 = t3 - xui3 + sc3;
    float m = fmaxf(fmaxf(l0, l1), fmaxf(l2, l3));
    float q0 = __expf(l0 - m), q1 = __expf(l1 - m), q2 = __expf(l2 - m), q3 = __expf(l3 - m);
    float inv = 1.0f / (q0 + q1 + q2 + q3);
    q0 *= inv; q1 *= inv; q2 *= inv; q3 *= inv;
    acc[0][0] += q0 * v.x; acc[0][1] += q0 * v.y; acc[0][2] += q0 * v.z; acc[0][3] += q0 * v.w;
    acc[1][0] += q1 * v.x; acc[1][1] += q1 * v.y; acc[1][2] += q1 * v.z; acc[1][3] += q1 * v.w;
    acc[2][0] += q2 * v.x; acc[2][1] += q2 * v.y; acc[2][2] += q2 * v.z; acc[2][3] += q2 * v.w;
    acc[3][0] += q3 * v.x; acc[3][1] += q3 * v.y; acc[3][2] += q3 * v.z; acc[3][3] += q3 * v.w;
  };

  // self loop (q = softmax(c)) on the e2==1 lanes
  if (e2 == 1) {
    float m = fmaxf(fmaxf(sc0, sc1), fmaxf(sc2, sc3));
    float q0 = __expf(sc0 - m), q1 = __expf(sc1 - m), q2 = __expf(sc2 - m), q3 = __expf(sc3 - m);
    float inv = 1.0f / (q0 + q1 + q2 + q3);
    q0 *= inv; q1 *= inv; q2 *= inv; q3 *= inv;
    acc[0][0] += q0 * xi.x; acc[0][1] += q0 * xi.y; acc[0][2] += q0 * xi.z; acc[0][3] += q0 * xi.w;
    acc[1][0] += q1 * xi.x; acc[1][1] += q1 * xi.y; acc[1][2] += q1 * xi.z; acc[1][3] += q1 * xi.w;
    acc[2][0] += q2 * xi.x; acc[2][1] += q2 * xi.y; acc[2][2] += q2 * xi.z; acc[2][3] += q2 * xi.w;
    acc[3][0] += q3 * xi.x; acc[3][1] += q3 * xi.y; acc[3][2] += q3 * xi.z; acc[3][3] += q3 * xi.w;
  }

  int r0 = row_start[i], r1 = row_start[i + 1];
  int r = r0 + e2;
  // batch-4: all 4 loads issued before any processing
  for (; r + 6 < r1; r += 8) {
    int j0 = csr[r], j1 = csr[r + 2], j2 = csr[r + 4], j3 = csr[r + 6];
    float4 v0 = *(const float4*)(x + j0 * 16 + f4 * 4);
    float4 v1 = *(const float4*)(x + j1 * 16 + f4 * 4);
    float4 v2 = *(const float4*)(x + j2 * 16 + f4 * 4);
    float4 v3 = *(const float4*)(x + j3 * 16 + f4 * 4);
    process(v0);
    process(v1);
    process(v2);
    process(v3);
  }
  // pair tail
  for (; r + 2 < r1; r += 4) {
    int ja = csr[r];
    int jb = csr[r + 2];
    float4 va = *(const float4*)(x + ja * 16 + f4 * 4);
    float4 vb = *(const float4*)(x + jb * 16 + f4 * 4);
    process(va);
    process(vb);
  }
  if (r < r1) {
    int j = csr[r];
    float4 v = *(const float4*)(x + j * 16 + f4 * 4);
    process(v);
  }

  // reduce over the e2 partner (lane ^ 4)
#pragma unroll
  for (int h = 0; h < 4; h++)
#pragma unroll
    for (int kl = 0; kl < 4; kl++) acc[h][kl] += __shfl_xor(acc[h][kl], 4);

  // per-lane partials for ALL 16 outputs from this lane's k-quarter (256 FMA)
  float p[4][4];  // [og][cc]
#pragma unroll
  for (int og = 0; og < 4; og++)
#pragma unroll
    for (int cc = 0; cc < 4; cc++) p[og][cc] = 0.f;
#pragma unroll
  for (int kl = 0; kl < 4; kl++) {
#pragma unroll
    for (int h = 0; h < 4; h++) {
      float a = acc[h][kl];
#pragma unroll
      for (int og = 0; og < 4; og++) {
        float4 w = sW[(h * 4 + og) * 16 + f4 * 4 + kl];
        p[og][0] += a * w.x; p[og][1] += a * w.y; p[og][2] += a * w.z; p[og][3] += a * w.w;
      }
    }
  }
  // reduce over the 4 f4 lanes
#pragma unroll
  for (int og = 0; og < 4; og++)
#pragma unroll
    for (int cc = 0; cc < 4; cc++) {
      float v = p[og][cc];
      v += __shfl_xor(v, 1);
      v += __shfl_xor(v, 2);
      p[og][cc] = v;
    }

  if (e2 == 0) {  // lane f4 writes output quarter og = f4 (compile-time selects)
    float invdeg = 1.0f / (float)(r1 - r0 + 1);
    float o0, o1, o2, o3;
    if (f4 == 0)      { o0 = p[0][0]; o1 = p[0][1]; o2 = p[0][2]; o3 = p[0][3]; }
    else if (f4 == 1) { o0 = p[1][0]; o1 = p[1][1]; o2 = p[1][2]; o3 = p[1][3]; }
    else if (f4 == 2) { o0 = p[2][0]; o1 = p[2][1]; o2 = p[2][2]; o3 = p[2][3]; }
    else              { o0 = p[3][0]; o1 = p[3][1]; o2 = p[3][2]; o3 = p[3][3]; }
    o0 = o0 * invdeg + sb[f4 * 4 + 0];
    o1 = o1 * invdeg + sb[f4 * 4 + 1];
    o2 = o2 * invdeg + sb[f4 * 4 + 2];
    o3 = o3 * invdeg + sb[f4 * 4 + 3];
    if (EPI == 1) {
      *(float4*)(out + i * 16 + f4 * 4) = make_float4(o0, o1, o2, o3);
    } else if (EPI == 0) {
      *(float4*)(out + i * 16 + f4 * 4) =
          make_float4(fmaxf(o0, 0.f), fmaxf(o1, 0.f), fmaxf(o2, 0.f), fmaxf(o3, 0.f));
    } else {
      *(float4*)(out2 + i * 16 + f4 * 4) = make_float4(o0, o1, o2, o3);
      *(float4*)(out + i * 16 + f4 * 4) =
          make_float4(fmaxf(o0, 0.f), fmaxf(o1, 0.f), fmaxf(o2, 0.f), fmaxf(o3, 0.f));
    }
  }
}

// ---------------- FeaSt heads=1 (softmax over 1 head == 1: pure mean agg + matvec) ----------------
// Cooperative 8-lane decomposition; batch-8 independent loads per lane.

template <int RELU>
__global__ void gather1_kernel(const float* __restrict__ x, const int* __restrict__ row_start,
                               const int* __restrict__ csr, const float* __restrict__ W,
                               const float* __restrict__ b, float* __restrict__ out, int n) {
  // transposed weight LDS: float idx = (og*16 + k)*4 + cc = W[k][og*4+cc]
  __shared__ float4 sW[64];
  __shared__ float sb[16];
  {
    int t = threadIdx.x;
    if (t < 256) {
      int cc = t & 3, k = (t >> 2) & 15, og = t >> 6;
      ((float*)sW)[t] = W[k * 16 + og * 4 + cc];
    }
    if (t < 16) sb[t] = b[t];
  }
  __syncthreads();
  int tid = blockIdx.x * blockDim.x + threadIdx.x;
  int i = tid >> 3;
  int e2 = (tid >> 2) & 1;
  int f4 = tid & 3;
  if (i >= n) return;

  float acc[4] = {0.f, 0.f, 0.f, 0.f};  // features f4*4 .. f4*4+4

  if (e2 == 1) {  // self loop
    float4 v = *(const float4*)(x + i * 16 + f4 * 4);
    acc[0] += v.x; acc[1] += v.y; acc[2] += v.z; acc[3] += v.w;
  }

  int r0 = row_start[i], r1 = row_start[i + 1];
  int r = r0 + e2;
  for (; r + 14 < r1; r += 16) {
    int j0 = csr[r],      j1 = csr[r + 2],  j2 = csr[r + 4],  j3 = csr[r + 6];
    int j4 = csr[r + 8],  j5 = csr[r + 10], j6 = csr[r + 12], j7 = csr[r + 14];
    float4 v0 = *(const float4*)(x + j0 * 16 + f4 * 4);
    float4 v1 = *(const float4*)(x + j1 * 16 + f4 * 4);
    float4 v2 = *(const float4*)(x + j2 * 16 + f4 * 4);
    float4 v3 = *(const float4*)(x + j3 * 16 + f4 * 4);
    float4 v4 = *(const float4*)(x + j4 * 16 + f4 * 4);
    float4 v5 = *(const float4*)(x + j5 * 16 + f4 * 4);
    float4 v6 = *(const float4*)(x + j6 * 16 + f4 * 4);
    float4 v7 = *(const float4*)(x + j7 * 16 + f4 * 4);
    acc[0] += (v0.x + v1.x) + (v2.x + v3.x) + (v4.x + v5.x) + (v6.x + v7.x);
    acc[1] += (v0.y + v1.y) + (v2.y + v3.y) + (v4.y + v5.y) + (v6.y + v7.y);
    acc[2] += (v0.z + v1.z) + (v2.z + v3.z) + (v4.z + v5.z) + (v6.z + v7.z);
    acc[3] += (v0.w + v1.w) + (v2.w + v3.w) + (v4.w + v5.w) + (v6.w + v7.w);
  }
  for (; r + 6 < r1; r += 8) {
    int j0 = csr[r], j1 = csr[r + 2], j2 = csr[r + 4], j3 = csr[r + 6];
    float4 v0 = *(const float4*)(x + j0 * 16 + f4 * 4);
    float4 v1 = *(const float4*)(x + j1 * 16 + f4 * 4);
    float4 v2 = *(const float4*)(x + j2 * 16 + f4 * 4);
    float4 v3 = *(const float4*)(x + j3 * 16 + f4 * 4);
    acc[0] += v0.x + v1.x + v2.x + v3.x;
    acc[1] += v0.y + v1.y + v2.y + v3.y;
    acc[2] += v0.z + v1.z + v2.z + v3.z;
    acc[3] += v0.w + v1.w + v2.w + v3.w;
  }
  for (; r < r1; r += 2) {
    int j = csr[r];
    float4 v = *(const float4*)(x + j * 16 + f4 * 4);
    acc[0] += v.x; acc[1] += v.y; acc[2] += v.z; acc[3] += v.w;
  }

#pragma unroll
  for (int kl = 0; kl < 4; kl++) acc[kl] += __shfl_xor(acc[kl], 4);

  // per-lane partials for all 16 outputs from this k-quarter (64 FMA)
  float p[4][4];
#pragma unroll
  for (int og = 0; og < 4; og++)
#pragma unroll
    for (int cc = 0; cc < 4; cc++) p[og][cc] = 0.f;
#pragma unroll
  for (int kl = 0; kl < 4; kl++) {
    float a = acc[kl];
#pragma unroll
    for (int og = 0; og < 4; og++) {
      float4 w = sW[og * 16 + f4 * 4 + kl];
      p[og][0] += a * w.x; p[og][1] += a * w.y; p[og][2] += a * w.z; p[og][3] += a * w.w;
    }
  }
#pragma unroll
  for (int og = 0; og < 4; og++)
#pragma unroll
    for (int cc = 0; cc < 4; cc++) {
      float v = p[og][cc];
      v += __shfl_xor(v, 1);
      v += __shfl_xor(v, 2);
      p[og][cc] = v;
    }

  if (e2 == 0) {
    float invdeg = 1.0f / (float)(r1 - r0 + 1);
    float o0, o1, o2, o3;
    if (f4 == 0)      { o0 = p[0][0]; o1 = p[0][1]; o2 = p[0][2]; o3 = p[0][3]; }
    else if (f4 == 1) { o0 = p[1][0]; o1 = p[1][1]; o2 = p[1][2]; o3 = p[1][3]; }
    else if (f4 == 2) { o0 = p[2][0]; o1 = p[2][1]; o2 = p[2][2]; o3 = p[2][3]; }
    else              { o0 = p[3][0]; o1 = p[3][1]; o2 = p[3][2]; o3 = p[3][3]; }
    o0 = o0 * invdeg + sb[f4 * 4 + 0];
    o1 = o1 * invdeg + sb[f4 * 4 + 1];
    o2 = o2 * invdeg + sb[f4 * 4 + 2];
    o3 = o3 * invdeg + sb[f4 * 4 + 3];
    if (RELU) {
      o0 = fmaxf(o0, 0.f); o1 = fmaxf(o1, 0.f); o2 = fmaxf(o2, 0.f); o3 = fmaxf(o3, 0.f);
    }
    *(float4*)(out + i * 16 + f4 * 4) = make_float4(o0, o1, o2, o3);
  }
}

// ---------------- BatchNorm ----------------

__global__ void bn_stats_kernel(const float* __restrict__ x, float* __restrict__ stats, int n) {
  __shared__ float wbuf[4][32];
  int t = threadIdx.x;
  float ls[16], lq[16];
#pragma unroll
  for (int k = 0; k < 16; k++) { ls[k] = 0.f; lq[k] = 0.f; }
  for (int i = blockIdx.x * blockDim.x + t; i < n; i += gridDim.x * blockDim.x) {
    const float4* xi = (const float4*)(x + i * 16);
#pragma unroll
    for (int g = 0; g < 4; g++) {
      float4 v = xi[g];
      ls[g * 4 + 0] += v.x; lq[g * 4 + 0] += v.x * v.x;
      ls[g * 4 + 1] += v.y; lq[g * 4 + 1] += v.y * v.y;
      ls[g * 4 + 2] += v.z; lq[g * 4 + 2] += v.z * v.z;
      ls[g * 4 + 3] += v.w; lq[g * 4 + 3] += v.w * v.w;
    }
  }
#pragma unroll
  for (int k = 0; k < 16; k++) {
    for (int off = 1; off < 64; off <<= 1) {
      ls[k] += __shfl_xor(ls[k], off);
      lq[k] += __shfl_xor(lq[k], off);
    }
  }
  int wid = t >> 6, lane = t & 63;
  if (lane < 16) wbuf[wid][lane] = ls[lane];
  if (lane >= 16 && lane < 32) wbuf[wid][lane] = lq[lane - 16];
  __syncthreads();
  if (t < 32) {
    float s = wbuf[0][t] + wbuf[1][t] + wbuf[2][t] + wbuf[3][t];
    atomicAdd(&stats[t], s);
  }
}

// RESID: out = relu(bn(x)) (+ r1 + r2 if RESID)
template <int RESID>
__global__ void bn_apply_kernel(const float* __restrict__ x, const float* __restrict__ stats,
                                const float* __restrict__ g, const float* __restrict__ be,
                                const float* __restrict__ r1, const float* __restrict__ r2,
                                float* __restrict__ out, int n) {
  __shared__ float sscale[16], sshift[16];
  int t = threadIdx.x;
  if (t < 16) {
    float invn = 1.0f / (float)n;
    float mu = stats[t] * invn;
    float var = stats[16 + t] * invn - mu * mu;
    float sc = g[t] * rsqrtf(var + 1e-5f);
    sscale[t] = sc;
    sshift[t] = be[t] - mu * sc;
  }
  __syncthreads();
  int i = blockIdx.x * blockDim.x + t;
  if (i >= n) return;
#pragma unroll
  for (int og = 0; og < 4; og++) {
    float4 v = *(const float4*)(x + i * 16 + og * 4);
    float o0 = fmaxf(v.x * sscale[og * 4 + 0] + sshift[og * 4 + 0], 0.f);
    float o1 = fmaxf(v.y * sscale[og * 4 + 1] + sshift[og * 4 + 1], 0.f);
    float o2 = fmaxf(v.z * sscale[og * 4 + 2] + sshift[og * 4 + 2], 0.f);
    float o3 = fmaxf(v.w * sscale[og * 4 + 3] + sshift[og * 4 + 3], 0.f);
    if (RESID) {
      float4 a = *(const float4*)(r1 + i * 16 + og * 4);
      float4 bb = *(const float4*)(r2 + i * 16 + og * 4);
      o0 += a.x + bb.x; o1 += a.y + bb.y; o2 += a.z + bb.z; o3 += a.w + bb.w;
    }
    *(float4*)(out + i * 16 + og * 4) = make_float4(o0, o1, o2, o3);
  }
}

// ---------------- MLP head: 16 ->64 relu ->64 relu ->16 relu ->1 sigmoid ----------------
// 4 threads per node; lane sub owns activations [sub*16, sub*16+16) (no spill).

__global__ void mlp_kernel(const float* __restrict__ h,
                           const float* __restrict__ lw1, const float* __restrict__ lb1,
                           const float* __restrict__ lw2, const float* __restrict__ lb2,
                           const float* __restrict__ lw3, const float* __restrict__ lb3,
                           const float* __restrict__ ow, const float* __restrict__ ob,
                           float* __restrict__ out, int n) {
  __shared__ float4 s1[256];   // 16x64, float4 idx = k*16 + og
  __shared__ float4 s2[1024];  // 64x64
  __shared__ float4 s3[256];   // 64x16
  __shared__ float sb1[64], sb2[64], sb3[16], sow[16], sob[1];
  {
    int t = threadIdx.x;
    for (int k = t; k < 1024; k += blockDim.x) ((float*)s1)[k] = lw1[k];
    for (int k = t; k < 4096; k += blockDim.x) ((float*)s2)[k] = lw2[k];
    for (int k = t; k < 1024; k += blockDim.x) ((float*)s3)[k] = lw3[k];
    if (t < 64) sb1[t] = lb1[t];
    if (t < 64) sb2[t] = lb2[t];
    if (t < 16) sb3[t] = lb3[t];
    if (t < 16) sow[t] = ow[t];
    if (t == 0) sob[0] = ob[0];
  }
  __syncthreads();
  int tid = blockIdx.x * blockDim.x + threadIdx.x;
  int i = tid >> 2;
  int sub = tid & 3;
  if (i >= n) return;

  float4 inq = *(const float4*)(h + i * 16 + sub * 4);
  float in4[4] = {inq.x, inq.y, inq.z, inq.w};

  float a[16];
#pragma unroll
  for (int g = 0; g < 4; g++) {
    int og = sub * 4 + g;
    a[g * 4 + 0] = sb1[og * 4 + 0]; a[g * 4 + 1] = sb1[og * 4 + 1];
    a[g * 4 + 2] = sb1[og * 4 + 2]; a[g * 4 + 3] = sb1[og * 4 + 3];
  }
#pragma unroll
  for (int k = 0; k < 16; k++) {
    float v = __shfl(in4[k & 3], k >> 2, 4);
#pragma unroll
    for (int g = 0; g < 4; g++) {
      float4 w = s1[k * 16 + sub * 4 + g];
      a[g * 4 + 0] += v * w.x; a[g * 4 + 1] += v * w.y;
      a[g * 4 + 2] += v * w.z; a[g * 4 + 3] += v * w.w;
    }
  }
#pragma unroll
  for (int k = 0; k < 16; k++) a[k] = fmaxf(a[k], 0.f);

  float b2[16];
#pragma unroll
  for (int g = 0; g < 4; g++) {
    int og = sub * 4 + g;
    b2[g * 4 + 0] = sb2[og * 4 + 0]; b2[g * 4 + 1] = sb2[og * 4 + 1];
    b2[g * 4 + 2] = sb2[og * 4 + 2]; b2[g * 4 + 3] = sb2[og * 4 + 3];
  }
#pragma unroll
  for (int k = 0; k < 64; k++) {
    float v = __shfl(a[k & 15], k >> 4, 4);
#pragma unroll
    for (int g = 0; g < 4; g++) {
      float4 w = s2[k * 16 + sub * 4 + g];
      b2[g * 4 + 0] += v * w.x; b2[g * 4 + 1] += v * w.y;
      b2[g * 4 + 2] += v * w.z; b2[g * 4 + 3] += v * w.w;
    }
  }
#pragma unroll
  for (int k = 0; k < 16; k++) b2[k] = fmaxf(b2[k], 0.f);

  float c0 = sb3[sub * 4 + 0], c1 = sb3[sub * 4 + 1], c2 = sb3[sub * 4 + 2], c3v = sb3[sub * 4 + 3];
#pragma unroll
  for (int k = 0; k < 64; k++) {
    float v = __shfl(b2[k & 15], k >> 4, 4);
    float4 w = s3[k * 4 + sub];
    c0 += v * w.x; c1 += v * w.y; c2 += v * w.z; c3v += v * w.w;
  }
  c0 = fmaxf(c0, 0.f); c1 = fmaxf(c1, 0.f); c2 = fmaxf(c2, 0.f); c3v = fmaxf(c3v, 0.f);

  float zp = c0 * sow[sub * 4 + 0] + c1 * sow[sub * 4 + 1] +
             c2 * sow[sub * 4 + 2] + c3v * sow[sub * 4 + 3];
  zp += __shfl_xor(zp, 1);
  zp += __shfl_xor(zp, 2);
  if (sub == 0) out[i] = 1.0f / (1.0f + __expf(-(zp + sob[0])));
}

// ---------------- launch ----------------

extern "C" void kernel_launch(void* const* d_in, const int* in_sizes, int n_in,
                              void* d_out, int out_size, void* d_ws, size_t ws_size,
                              hipStream_t stream) {
  const float* x = (const float*)d_in[0];
  const int* ei = (const int*)d_in[1];
  const int N = in_sizes[0] / 16;
  const int E = in_sizes[1] / 2;
  const int* srcp = ei;
  const int* dstp = ei + E;

  const float* W1 = (const float*)d_in[2];  const float* u1 = (const float*)d_in[3];
  const float* c1 = (const float*)d_in[4];  const float* b1 = (const float*)d_in[5];
  const float* W2 = (const float*)d_in[6];  const float* u2 = (const float*)d_in[7];
  const float* c2 = (const float*)d_in[8];  const float* b2 = (const float*)d_in[9];
  const float* W3 = (const float*)d_in[10]; const float* u3 = (const float*)d_in[11];
  const float* c3 = (const float*)d_in[12]; const float* b3 = (const float*)d_in[13];
  const float* W4 = (const float*)d_in[14]; const float* b4 = (const float*)d_in[17];
  const float* W5 = (const float*)d_in[18]; const float* b5 = (const float*)d_in[21];
  const float* W6 = (const float*)d_in[22]; const float* b6 = (const float*)d_in[25];
  const float* g1 = (const float*)d_in[26]; const float* be1 = (const float*)d_in[27];
  const float* g2 = (const float*)d_in[28]; const float* be2 = (const float*)d_in[29];
  const float* lw1 = (const float*)d_in[30]; const float* lb1 = (const float*)d_in[31];
  const float* lw2 = (const float*)d_in[32]; const float* lb2 = (const float*)d_in[33];
  const float* lw3 = (const float*)d_in[34]; const float* lb3 = (const float*)d_in[35];
  const float* ow = (const float*)d_in[36]; const float* ob = (const float*)d_in[37];
  float* out = (float*)d_out;

  char* ws = (char*)d_ws;
  size_t off = 0;
  auto alloc = [&](size_t bytes) -> void* {
    void* p = ws + off;
    off = (off + bytes + 255) & ~(size_t)255;
    return p;
  };
  int* row_start = (int*)alloc((size_t)(N + 1) * 4);
  int* csr = (int*)alloc((size_t)E * 4);
  float* bufA = (float*)alloc((size_t)N * 16 * 4);
  float* bufB = (float*)alloc((size_t)N * 16 * 4);
  float* h2b = (float*)alloc((size_t)N * 16 * 4);
  float* h4b = (float*)alloc((size_t)N * 16 * 4);
  float* tmp = (float*)alloc((size_t)N * 16 * 4);
  float* stats = (float*)alloc(32 * 4);
  const int NBUK = (N + (1 << BSHIFT) - 1) >> BSHIFT;
  int* bcnt = (int*)alloc((size_t)NBUK * 4);
  int* gbase = (int*)alloc((size_t)(NBUK + 1) * 4);
  int* gbcur = (int*)alloc((size_t)NBUK * 4);
  // pairs staging (E * 8B = 12.8MB) aliases bufA+bufB (contiguous 12.8MB),
  // unused until layer 1 (CSR build completes first).
  int2* pairs = (int2*)bufA;

  const int NB = (N + BLK - 1) / BLK;        // node-parallel grid
  const int NG4 = (4 * N + BLK - 1) / BLK;   // 4-threads-per-node (mlp)
  const int NG8 = (8 * N + BLK - 1) / BLK;   // 8-threads-per-node (gathers)
  const int NT = (E + TILE - 1) / TILE;      // edge tiles

  // ---- CSR build (per call; ws is re-poisoned every launch) ----
  hipMemsetAsync(bcnt, 0, (size_t)NBUK * 4, stream);
  bhist_kernel<<<NT, BLK, 0, stream>>>(dstp, bcnt, E, NBUK);
  bscan_kernel<<<1, BLK, 0, stream>>>(bcnt, gbase, gbcur, NBUK, E);
  scatter_pairs_lds_kernel<<<NT, BLK, 0, stream>>>(srcp, dstp, gbcur, pairs, E, NBUK);
  bucket_build_kernel<<<NBUK, BLK, 0, stream>>>(pairs, gbase, row_start, csr, N, NBUK, E);

  // ---- Layer 1: h = relu(feast4(x)) -> bufA ----
  gather4_kernel<0><<<NG8, BLK, 0, stream>>>(x, row_start, csr, W1, u1, c1, b1, bufA, nullptr, N);

  // ---- Layer 2: h2 = feast4(bufA) (raw -> h2b), relu -> bufB ----
  gather4_kernel<2><<<NG8, BLK, 0, stream>>>(bufA, row_start, csr, W2, u2, c2, b2, bufB, h2b, N);

  // ---- Layer 3: h3 = relu(bn(feast4(bufB))) -> bufA ----
  gather4_kernel<1><<<NG8, BLK, 0, stream>>>(bufB, row_start, csr, W3, u3, c3, b3, tmp, nullptr, N);
  hipMemsetAsync(stats, 0, 32 * 4, stream);
  bn_stats_kernel<<<256, BLK, 0, stream>>>(tmp, stats, N);
  bn_apply_kernel<0><<<NB, BLK, 0, stream>>>(tmp, stats, g1, be1, nullptr, nullptr, bufA, N);

  // ---- Layer 4: h4 = relu(feast1(bufA)) -> h4b ----
  gather1_kernel<1><<<NG8, BLK, 0, stream>>>(bufA, row_start, csr, W4, b4, h4b, N);

  // ---- Layer 5: h5 = relu(feast1(h4b)) -> bufB ----
  gather1_kernel<1><<<NG8, BLK, 0, stream>>>(h4b, row_start, csr, W5, b5, bufB, N);

  // ---- Layer 6: h6 = relu(bn(feast1(bufB))) + h2b + h4b -> bufA ----
  gather1_kernel<0><<<NG8, BLK, 0, stream>>>(bufB, row_start, csr, W6, b6, tmp, N);
  hipMemsetAsync(stats, 0, 32 * 4, stream);
  bn_stats_kernel<<<256, BLK, 0, stream>>>(tmp, stats, N);
  bn_apply_kernel<1><<<NB, BLK, 0, stream>>>(tmp, stats, g2, be2, h2b, h4b, bufA, N);

  // ---- MLP head -> out ----
  mlp_kernel<<<NG4, BLK, 0, stream>>>(bufA, lw1, lb1, lw2, lb2, lw3, lb3, ow, ob, out, N);
}